// Round 11
// baseline (289.107 us; speedup 1.0000x reference)
//
#include <hip/hip_runtime.h>
#include <hip/hip_bf16.h>

typedef short bf16x8 __attribute__((ext_vector_type(8)));
typedef float f32x4 __attribute__((ext_vector_type(4)));

// --- bf16 pack helpers (RNE) ----------------------------------------------
__device__ __forceinline__ unsigned pack_bf16x2(float lo, float hi) {
    unsigned a = __builtin_bit_cast(unsigned, lo);
    unsigned b = __builtin_bit_cast(unsigned, hi);
    a += 0x7fffu + ((a >> 16) & 1u);
    b += 0x7fffu + ((b >> 16) & 1u);
    return (a >> 16) | (b & 0xffff0000u);
}
__device__ __forceinline__ unsigned short bf16r(float f) {
    unsigned a = __builtin_bit_cast(unsigned, f);
    a += 0x7fffu + ((a >> 16) & 1u);
    return (unsigned short)(a >> 16);
}
__device__ __forceinline__ float bf_lo(unsigned u) {
    return __builtin_bit_cast(float, u << 16);
}
__device__ __forceinline__ float bf_hi(unsigned u) {
    return __builtin_bit_cast(float, u & 0xffff0000u);
}

// ---------------------------------------------------------------------------
// prep: pack W1/W2 into MFMA-B frag-linear bf16 layout.
// ---------------------------------------------------------------------------
__global__ void prep_kernel(const float* __restrict__ W1, const float* __restrict__ W2,
                            unsigned* __restrict__ Wb1, unsigned* __restrict__ Wb2) {
    const int t = blockIdx.x * 256 + threadIdx.x;
    if (t < 2048) {
        const int lane = t & 63, kt = (t >> 6) & 3, ct = t >> 8;
        const int col = ct * 16 + (lane & 15);
        const int kb = 8 * (lane >> 4) + 32 * kt;
        uint4 u;
        u.x = pack_bf16x2(W1[(size_t)(kb + 0) * 128 + col], W1[(size_t)(kb + 1) * 128 + col]);
        u.y = pack_bf16x2(W1[(size_t)(kb + 2) * 128 + col], W1[(size_t)(kb + 3) * 128 + col]);
        u.z = pack_bf16x2(W1[(size_t)(kb + 4) * 128 + col], W1[(size_t)(kb + 5) * 128 + col]);
        u.w = pack_bf16x2(W1[(size_t)(kb + 6) * 128 + col], W1[(size_t)(kb + 7) * 128 + col]);
        *(uint4*)&Wb1[t * 4] = u;
    } else if (t < 3072) {
        const int s = t - 2048;
        const int lane = s & 63, kt = (s >> 6) & 3, ct = s >> 8;
        const int col = ct * 16 + (lane & 15);
        const int kb = 8 * (lane >> 4) + 32 * kt;
        uint4 u;
        u.x = pack_bf16x2(W2[(size_t)(kb + 0) * 64 + col], W2[(size_t)(kb + 1) * 64 + col]);
        u.y = pack_bf16x2(W2[(size_t)(kb + 2) * 64 + col], W2[(size_t)(kb + 3) * 64 + col]);
        u.z = pack_bf16x2(W2[(size_t)(kb + 4) * 64 + col], W2[(size_t)(kb + 5) * 64 + col]);
        u.w = pack_bf16x2(W2[(size_t)(kb + 6) * 64 + col], W2[(size_t)(kb + 7) * 64 + col]);
        *(uint4*)&Wb2[s * 4] = u;
    }
}

// ---------------------------------------------------------------------------
// FUSED gemm1 + rank_count (heterogeneous block-split; independent work).
// Blocks [0,nblk): MFMA GEMM h1 = bf16(x @ W1).  Blocks [nblk, nblk+512):
// rank_count — returning atomics whose latency co-schedules with the GEMM
// blocks on other waves/CUs (both resident: no LDS, ~64 VGPR).
// ---------------------------------------------------------------------------
__global__ __launch_bounds__(256) void gemm1_rank_kernel(const float* __restrict__ x,
                                                         const unsigned* __restrict__ Wb1,
                                                         unsigned short* __restrict__ h1,
                                                         int N, int nblk,
                                                         const int* __restrict__ ei, int E,
                                                         int* __restrict__ deg,
                                                         int* __restrict__ rank) {
    if ((int)blockIdx.x >= nblk) {
        // ---- rank_count path: 8 independent returning atomics in flight ----
        const int nb = gridDim.x - nblk;
        const int stride = nb * 256;
        int e = (blockIdx.x - nblk) * 256 + threadIdx.x;
        for (; e + 7 * stride < E; e += 8 * stride) {
            int d[8], r[8];
#pragma unroll
            for (int i = 0; i < 8; ++i) d[i] = ei[E + e + i * stride];
#pragma unroll
            for (int i = 0; i < 8; ++i) r[i] = atomicAdd(&deg[d[i]], 1);
#pragma unroll
            for (int i = 0; i < 8; ++i) rank[e + i * stride] = r[i];
        }
        for (; e < E; e += stride)
            rank[e] = atomicAdd(&deg[ei[E + e]], 1);
        return;
    }
    // ---- GEMM path: wave = 16 rows ----
    const int wid = threadIdx.x >> 6, lane = threadIdx.x & 63;
    const int row0 = (blockIdx.x * 4 + wid) * 16;
    if (row0 >= N) return;
    const int g = lane >> 4;
    const int mrow = min(row0 + (lane & 15), N - 1);

    bf16x8 afrag[4];
#pragma unroll
    for (int kt = 0; kt < 4; ++kt) {
        const float4 v0 = *(const float4*)&x[(size_t)mrow * 128 + g * 8 + kt * 32];
        const float4 v1 = *(const float4*)&x[(size_t)mrow * 128 + g * 8 + kt * 32 + 4];
        uint4 u;
        u.x = pack_bf16x2(v0.x, v0.y);
        u.y = pack_bf16x2(v0.z, v0.w);
        u.z = pack_bf16x2(v1.x, v1.y);
        u.w = pack_bf16x2(v1.z, v1.w);
        afrag[kt] = __builtin_bit_cast(bf16x8, u);
    }
#pragma unroll
    for (int ct = 0; ct < 8; ++ct) {
        f32x4 acc = {0.f, 0.f, 0.f, 0.f};
#pragma unroll
        for (int kt = 0; kt < 4; ++kt) {
            const bf16x8 b = __builtin_bit_cast(bf16x8, *(const uint4*)&Wb1[((ct * 4 + kt) * 64 + lane) * 4]);
            acc = __builtin_amdgcn_mfma_f32_16x16x32_bf16(afrag[kt], b, acc, 0, 0, 0);
        }
        const int col = ct * 16 + (lane & 15);
#pragma unroll
        for (int r = 0; r < 4; ++r) {
            const int row = row0 + g * 4 + r;
            if (row < N) h1[(size_t)row * 128 + col] = bf16r(acc[r]);
        }
    }
}

// ---------------------------------------------------------------------------
// GEMM2, MFMA: h2[N][64] bf16 = x2(bf16) @ bf16(W2).
// ---------------------------------------------------------------------------
__global__ __launch_bounds__(256) void gemm2_kernel(const unsigned* __restrict__ x2p,
                                                    const unsigned* __restrict__ Wb2,
                                                    unsigned short* __restrict__ h2,
                                                    int N) {
    const int wid = threadIdx.x >> 6, lane = threadIdx.x & 63;
    const int row0 = (blockIdx.x * 4 + wid) * 16;
    if (row0 >= N) return;
    const int g = lane >> 4;
    const int mrow = min(row0 + (lane & 15), N - 1);

    bf16x8 afrag[4];
#pragma unroll
    for (int kt = 0; kt < 4; ++kt)
        afrag[kt] = __builtin_bit_cast(bf16x8, *(const uint4*)&x2p[(size_t)mrow * 64 + g * 4 + kt * 16]);
#pragma unroll
    for (int ct = 0; ct < 4; ++ct) {
        f32x4 acc = {0.f, 0.f, 0.f, 0.f};
#pragma unroll
        for (int kt = 0; kt < 4; ++kt) {
            const bf16x8 b = __builtin_bit_cast(bf16x8, *(const uint4*)&Wb2[((ct * 4 + kt) * 64 + lane) * 4]);
            acc = __builtin_amdgcn_mfma_f32_16x16x32_bf16(afrag[kt], b, acc, 0, 0, 0);
        }
        const int col = ct * 16 + (lane & 15);
#pragma unroll
        for (int r = 0; r < 4; ++r) {
            const int row = row0 + g * 4 + r;
            if (row < N) h2[(size_t)row * 64 + col] = bf16r(acc[r]);
        }
    }
}

// ---------------------------------------------------------------------------
// FUSED csr_fill + escore1 (independent after scan_p3 & gemm1).
// Blocks [0, fillB): atomic-free CSR fill.  Blocks [fillB, ...): layer-1
// scores (2 nodes/wave, lane covers 4 channels, 3-shfl head reduce).
// ---------------------------------------------------------------------------
__global__ __launch_bounds__(256) void fill_escore1_kernel(const int* __restrict__ ei, int E, int N,
                                                           const int* __restrict__ rowstart,
                                                           const int* __restrict__ rank,
                                                           int* __restrict__ csr_src, int fillB,
                                                           const unsigned* __restrict__ h1u,
                                                           const float* __restrict__ asrc,
                                                           const float* __restrict__ adst,
                                                           float* __restrict__ es,
                                                           float* __restrict__ ed) {
    if ((int)blockIdx.x < fillB) {
        const int e = blockIdx.x * 256 + threadIdx.x;
        if (e < E) {
            const int d = ei[E + e];
            csr_src[rowstart[d] + rank[e]] = ei[e];
        } else if (e < E + N) {
            const int d = e - E;
            csr_src[rowstart[d + 1] - 1] = d;
        }
        return;
    }
    const int lane = threadIdx.x & 63;
    const int n = (((blockIdx.x - fillB) * 256 + threadIdx.x) >> 6) * 2 + (lane >> 5);
    if (n >= N) return;
    const int c = lane & 31;
    const uint2 u = *(const uint2*)&h1u[(size_t)n * 64 + c * 2];
    const float4 av = *(const float4*)&asrc[c * 4];
    const float4 dv = *(const float4*)&adst[c * 4];
    const float v0 = bf_lo(u.x), v1 = bf_hi(u.x), v2 = bf_lo(u.y), v3 = bf_hi(u.y);
    float s = v0 * av.x + v1 * av.y + v2 * av.z + v3 * av.w;
    float d = v0 * dv.x + v1 * dv.y + v2 * dv.z + v3 * dv.w;
#pragma unroll
    for (int off = 1; off <= 4; off <<= 1) {
        s += __shfl_xor(s, off);
        d += __shfl_xor(d, off);
    }
    if ((c & 7) == 0) {
        es[n * 4 + (c >> 3)] = s;
        ed[n * 4 + (c >> 3)] = d;
    }
}

// Scores layer 2: single head over 64 ch; TWO nodes per wave (32 lanes each).
__global__ __launch_bounds__(256) void escore2_kernel(const unsigned* __restrict__ h2u,
                                                      const float* __restrict__ asrc,
                                                      const float* __restrict__ adst,
                                                      float* __restrict__ es,
                                                      float* __restrict__ ed, int N) {
    const int lane = threadIdx.x & 63;
    const int n = ((blockIdx.x * 256 + threadIdx.x) >> 6) * 2 + (lane >> 5);
    if (n >= N) return;
    const int c = lane & 31;
    const unsigned u = h2u[(size_t)n * 32 + c];
    const float lo = bf_lo(u), hi = bf_hi(u);
    float s = lo * asrc[2 * c] + hi * asrc[2 * c + 1];
    float d = lo * adst[2 * c] + hi * adst[2 * c + 1];
#pragma unroll
    for (int off = 1; off <= 16; off <<= 1) {
        s += __shfl_xor(s, off);
        d += __shfl_xor(d, off);
    }
    if (c == 0) { es[n] = s; ed[n] = d; }
}

// ---------------------------------------------------------------------------
// CSR scan: exclusive scan of (deg+1); self-loop takes LAST slot per segment.
// ---------------------------------------------------------------------------
__global__ __launch_bounds__(256) void scan_p1_kernel(const int* __restrict__ deg,
                                                      int* __restrict__ excl,
                                                      int* __restrict__ bsum, int N) {
    __shared__ int lds[256];
    const int tid = threadIdx.x;
    const int base = blockIdx.x * 2048;
    const int idx0 = base + tid * 8;
    int v[8];
    int s = 0;
#pragma unroll
    for (int i = 0; i < 8; ++i) {
        v[i] = (idx0 + i < N) ? deg[idx0 + i] + 1 : 0;  // +1 = self-loop
        s += v[i];
    }
    lds[tid] = s;
    __syncthreads();
    for (int off = 1; off < 256; off <<= 1) {
        int t = (tid >= off) ? lds[tid - off] : 0;
        __syncthreads();
        lds[tid] += t;
        __syncthreads();
    }
    const int texcl = lds[tid] - s;
    if (tid == 255) bsum[blockIdx.x] = lds[255];
    int run = texcl;
#pragma unroll
    for (int i = 0; i < 8; ++i) {
        if (idx0 + i < N) excl[idx0 + i] = run;
        run += v[i];
    }
}

__global__ void scan_p2_kernel(int* __restrict__ bsum, int nchunks) {
    const int lane = threadIdx.x;
    int v = (lane < nchunks) ? bsum[lane] : 0;
    const int orig = v;
#pragma unroll
    for (int off = 1; off < 64; off <<= 1) {
        int t = __shfl_up(v, off);
        if (lane >= off) v += t;
    }
    if (lane < nchunks) bsum[lane] = v - orig;
}

__global__ void scan_p3_kernel(const int* __restrict__ excl, const int* __restrict__ bsum,
                               int* __restrict__ rowstart, int N, int Etot) {
    const int i = blockIdx.x * 256 + threadIdx.x;
    if (i < N) rowstart[i] = excl[i] + bsum[i >> 11];
    if (i == 0) rowstart[N] = Etot;
}

// ---------------------------------------------------------------------------
// Aggregation layer 1, GROUPED: 4 nodes/wave, 16 lanes/node, lane = 8 ch
// (uint4 gather).  4-edge unroll -> 4 outstanding gathers per lane.
// Invalid slots get p=0 (branch-free).
// ---------------------------------------------------------------------------
__global__ __launch_bounds__(256) void aggregate1_kernel(const unsigned* __restrict__ h1p,
                                                         const float* __restrict__ es,
                                                         const float* __restrict__ ed,
                                                         const int* __restrict__ rowstart,
                                                         const int* __restrict__ csr_src,
                                                         const float* __restrict__ b,
                                                         unsigned* __restrict__ x2p, int N) {
    const int lane = threadIdx.x & 63;
    const int w = (blockIdx.x * 256 + threadIdx.x) >> 6;
    const int l16 = lane & 15;
    const int n = w * 4 + (lane >> 4);
    const int hh = l16 >> 2;  // head 0..3
    const bool valid = n < N;
    const int nc = valid ? n : N - 1;
    const int beg = rowstart[nc];
    const int deg = valid ? rowstart[nc + 1] - beg : 0;
    const float edv = ed[nc * 4 + hh];

    int dmax = deg;
    dmax = max(dmax, __shfl_xor(dmax, 16));
    dmax = max(dmax, __shfl_xor(dmax, 32));

    float acc0 = 0.f, acc1 = 0.f, acc2 = 0.f, acc3 = 0.f;
    float acc4 = 0.f, acc5 = 0.f, acc6 = 0.f, acc7 = 0.f;
    float den = 0.f;
    for (int j = 0; j < dmax; j += 4) {
        const bool va = j < deg, vb = j + 1 < deg, vc = j + 2 < deg, vd = j + 3 < deg;
        const int pa_ = va ? beg + j : 0;
        const int pb_ = vb ? beg + j + 1 : 0;
        const int pc_ = vc ? beg + j + 2 : 0;
        const int pd_ = vd ? beg + j + 3 : 0;
        const int sa = csr_src[pa_];
        const int sb = csr_src[pb_];
        const int sc = csr_src[pc_];
        const int sd = csr_src[pd_];
        const uint4 ua = *(const uint4*)&h1p[(size_t)sa * 64 + l16 * 4];
        const uint4 ub = *(const uint4*)&h1p[(size_t)sb * 64 + l16 * 4];
        const uint4 uc = *(const uint4*)&h1p[(size_t)sc * 64 + l16 * 4];
        const uint4 ud = *(const uint4*)&h1p[(size_t)sd * 64 + l16 * 4];
        const float xa = es[sa * 4 + hh] + edv;
        const float xb = es[sb * 4 + hh] + edv;
        const float xc = es[sc * 4 + hh] + edv;
        const float xd = es[sd * 4 + hh] + edv;
        float qa = __expf(fmaxf(xa, 0.2f * xa));
        float qb = __expf(fmaxf(xb, 0.2f * xb));
        float qc = __expf(fmaxf(xc, 0.2f * xc));
        float qd = __expf(fmaxf(xd, 0.2f * xd));
        qa = va ? qa : 0.f;
        qb = vb ? qb : 0.f;
        qc = vc ? qc : 0.f;
        qd = vd ? qd : 0.f;
        den += (qa + qb) + (qc + qd);
        acc0 = fmaf(qa, bf_lo(ua.x), fmaf(qb, bf_lo(ub.x), fmaf(qc, bf_lo(uc.x), fmaf(qd, bf_lo(ud.x), acc0))));
        acc1 = fmaf(qa, bf_hi(ua.x), fmaf(qb, bf_hi(ub.x), fmaf(qc, bf_hi(uc.x), fmaf(qd, bf_hi(ud.x), acc1))));
        acc2 = fmaf(qa, bf_lo(ua.y), fmaf(qb, bf_lo(ub.y), fmaf(qc, bf_lo(uc.y), fmaf(qd, bf_lo(ud.y), acc2))));
        acc3 = fmaf(qa, bf_hi(ua.y), fmaf(qb, bf_hi(ub.y), fmaf(qc, bf_hi(uc.y), fmaf(qd, bf_hi(ud.y), acc3))));
        acc4 = fmaf(qa, bf_lo(ua.z), fmaf(qb, bf_lo(ub.z), fmaf(qc, bf_lo(uc.z), fmaf(qd, bf_lo(ud.z), acc4))));
        acc5 = fmaf(qa, bf_hi(ua.z), fmaf(qb, bf_hi(ub.z), fmaf(qc, bf_hi(uc.z), fmaf(qd, bf_hi(ud.z), acc5))));
        acc6 = fmaf(qa, bf_lo(ua.w), fmaf(qb, bf_lo(ub.w), fmaf(qc, bf_lo(uc.w), fmaf(qd, bf_lo(ud.w), acc6))));
        acc7 = fmaf(qa, bf_hi(ua.w), fmaf(qb, bf_hi(ub.w), fmaf(qc, bf_hi(uc.w), fmaf(qd, bf_hi(ud.w), acc7))));
    }
    if (valid) {
        const float inv = __builtin_amdgcn_rcpf(den);
        const float4 ba = *(const float4*)&b[l16 * 8];
        const float4 bb = *(const float4*)&b[l16 * 8 + 4];
        float o0 = fmaf(acc0, inv, ba.x); o0 = fmaxf(o0, 0.01f * o0);
        float o1 = fmaf(acc1, inv, ba.y); o1 = fmaxf(o1, 0.01f * o1);
        float o2 = fmaf(acc2, inv, ba.z); o2 = fmaxf(o2, 0.01f * o2);
        float o3 = fmaf(acc3, inv, ba.w); o3 = fmaxf(o3, 0.01f * o3);
        float o4 = fmaf(acc4, inv, bb.x); o4 = fmaxf(o4, 0.01f * o4);
        float o5 = fmaf(acc5, inv, bb.y); o5 = fmaxf(o5, 0.01f * o5);
        float o6 = fmaf(acc6, inv, bb.z); o6 = fmaxf(o6, 0.01f * o6);
        float o7 = fmaf(acc7, inv, bb.w); o7 = fmaxf(o7, 0.01f * o7);
        uint4 o;
        o.x = pack_bf16x2(o0, o1);
        o.y = pack_bf16x2(o2, o3);
        o.z = pack_bf16x2(o4, o5);
        o.w = pack_bf16x2(o6, o7);
        *(uint4*)&x2p[(size_t)n * 64 + l16 * 4] = o;
    }
}

// ---------------------------------------------------------------------------
// Aggregation layer 2, GROUPED: 4 nodes/wave, 16 lanes/node, lane = 4 ch
// (uint2 gather).  Single head.  4-edge unroll.
// ---------------------------------------------------------------------------
__global__ __launch_bounds__(256) void aggregate2_kernel(const unsigned* __restrict__ h2p,
                                                         const float* __restrict__ es,
                                                         const float* __restrict__ ed,
                                                         const int* __restrict__ rowstart,
                                                         const int* __restrict__ csr_src,
                                                         const float* __restrict__ b,
                                                         float* __restrict__ out, int N) {
    const int lane = threadIdx.x & 63;
    const int w = (blockIdx.x * 256 + threadIdx.x) >> 6;
    const int l16 = lane & 15;
    const int n = w * 4 + (lane >> 4);
    const bool valid = n < N;
    const int nc = valid ? n : N - 1;
    const int beg = rowstart[nc];
    const int deg = valid ? rowstart[nc + 1] - beg : 0;
    const float edv = ed[nc];

    int dmax = deg;
    dmax = max(dmax, __shfl_xor(dmax, 16));
    dmax = max(dmax, __shfl_xor(dmax, 32));

    float acc0 = 0.f, acc1 = 0.f, acc2 = 0.f, acc3 = 0.f;
    float den = 0.f;
    for (int j = 0; j < dmax; j += 4) {
        const bool va = j < deg, vb = j + 1 < deg, vc = j + 2 < deg, vd = j + 3 < deg;
        const int pa_ = va ? beg + j : 0;
        const int pb_ = vb ? beg + j + 1 : 0;
        const int pc_ = vc ? beg + j + 2 : 0;
        const int pd_ = vd ? beg + j + 3 : 0;
        const int sa = csr_src[pa_];
        const int sb = csr_src[pb_];
        const int sc = csr_src[pc_];
        const int sd = csr_src[pd_];
        const uint2 ua = *(const uint2*)&h2p[(size_t)sa * 32 + l16 * 2];
        const uint2 ub = *(const uint2*)&h2p[(size_t)sb * 32 + l16 * 2];
        const uint2 uc = *(const uint2*)&h2p[(size_t)sc * 32 + l16 * 2];
        const uint2 ud = *(const uint2*)&h2p[(size_t)sd * 32 + l16 * 2];
        const float xa = es[sa] + edv;
        const float xb = es[sb] + edv;
        const float xc = es[sc] + edv;
        const float xd = es[sd] + edv;
        float qa = __expf(fmaxf(xa, 0.2f * xa));
        float qb = __expf(fmaxf(xb, 0.2f * xb));
        float qc = __expf(fmaxf(xc, 0.2f * xc));
        float qd = __expf(fmaxf(xd, 0.2f * xd));
        qa = va ? qa : 0.f;
        qb = vb ? qb : 0.f;
        qc = vc ? qc : 0.f;
        qd = vd ? qd : 0.f;
        den += (qa + qb) + (qc + qd);
        acc0 = fmaf(qa, bf_lo(ua.x), fmaf(qb, bf_lo(ub.x), fmaf(qc, bf_lo(uc.x), fmaf(qd, bf_lo(ud.x), acc0))));
        acc1 = fmaf(qa, bf_hi(ua.x), fmaf(qb, bf_hi(ub.x), fmaf(qc, bf_hi(uc.x), fmaf(qd, bf_hi(ud.x), acc1))));
        acc2 = fmaf(qa, bf_lo(ua.y), fmaf(qb, bf_lo(ub.y), fmaf(qc, bf_lo(uc.y), fmaf(qd, bf_lo(ud.y), acc2))));
        acc3 = fmaf(qa, bf_hi(ua.y), fmaf(qb, bf_hi(ub.y), fmaf(qc, bf_hi(uc.y), fmaf(qd, bf_hi(ud.y), acc3))));
    }
    if (valid) {
        const float inv = __builtin_amdgcn_rcpf(den);
        const float4 bv = *(const float4*)&b[l16 * 4];
        float4 o;
        o.x = fmaf(acc0, inv, bv.x);
        o.y = fmaf(acc1, inv, bv.y);
        o.z = fmaf(acc2, inv, bv.z);
        o.w = fmaf(acc3, inv, bv.w);
        *(float4*)&out[(size_t)n * 64 + l16 * 4] = o;
    }
}

// ---------------------------------------------------------------------------
extern "C" void kernel_launch(void* const* d_in, const int* in_sizes, int n_in,
                              void* d_out, int out_size, void* d_ws, size_t ws_size,
                              hipStream_t stream) {
    const float* x     = (const float*)d_in[0];
    const int*   ei    = (const int*)d_in[1];
    const float* W1    = (const float*)d_in[2];
    const float* asrc1 = (const float*)d_in[3];
    const float* adst1 = (const float*)d_in[4];
    const float* b1    = (const float*)d_in[5];
    const float* W2    = (const float*)d_in[6];
    const float* asrc2 = (const float*)d_in[7];
    const float* adst2 = (const float*)d_in[8];
    const float* b2    = (const float*)d_in[9];
    float* out = (float*)d_out;

    const int N = in_sizes[0] / 128;
    const int E = in_sizes[1] / 2;
    const int Etot = E + N;

    // workspace layout (~83 MB)
    char* p = (char*)d_ws;
    auto alloc = [&](size_t bytes) {
        char* q = p;
        p += (bytes + 255) & ~size_t(255);
        return q;
    };
    unsigned short* h1 = (unsigned short*)alloc((size_t)N * 128 * 2);  // bf16 h1
    unsigned* x2p      = (unsigned*)alloc((size_t)N * 64 * 4);         // bf16x2 x2
    unsigned short* h2 = (unsigned short*)alloc((size_t)N * 64 * 2);   // bf16 h2
    float* es1      = (float*)alloc((size_t)N * 4 * 4);
    float* ed1      = (float*)alloc((size_t)N * 4 * 4);
    float* es2      = (float*)alloc((size_t)N * 4);
    float* ed2      = (float*)alloc((size_t)N * 4);
    int*   deg      = (int*)alloc((size_t)N * 4);
    int*   excl     = (int*)alloc((size_t)N * 4);
    int*   bsum     = (int*)alloc(1024);
    int*   rowstart = (int*)alloc((size_t)(N + 1) * 4);
    int*   rank     = (int*)alloc((size_t)E * 4);
    int*   csr_src  = (int*)alloc((size_t)Etot * 4);
    unsigned* Wb1   = (unsigned*)alloc(2048 * 16);
    unsigned* Wb2   = (unsigned*)alloc(1024 * 16);

    const int nblk16 = (N + 63) / 64;       // MFMA gemms: 4 waves x 16 rows
    const int nwb2 = (N / 2 + 3) / 4 + 1;   // 2-nodes-per-wave kernels
    const int nwb4 = (N + 15) / 16;         // 4-nodes-per-wave agg kernels
    const int fillB = (Etot + 255) / 256;
    const int nchunks = (N + 2047) / 2048;  // <= 64 required (N <= 131072)

    // weight prep + degree init
    prep_kernel<<<12, 256, 0, stream>>>(W1, W2, Wb1, Wb2);
    hipMemsetAsync(deg, 0, (size_t)N * 4, stream);

    // layer 1 projection (MFMA) || rank_count (block-split fusion)
    gemm1_rank_kernel<<<nblk16 + 512, 256, 0, stream>>>(x, Wb1, h1, N, nblk16,
                                                        ei, E, deg, rank);

    // CSR scan
    scan_p1_kernel<<<nchunks, 256, 0, stream>>>(deg, excl, bsum, N);
    scan_p2_kernel<<<1, 64, 0, stream>>>(bsum, nchunks);
    scan_p3_kernel<<<(N + 255) / 256, 256, 0, stream>>>(excl, bsum, rowstart, N, Etot);

    // csr_fill || escore1 (block-split fusion)
    fill_escore1_kernel<<<fillB + nwb2, 256, 0, stream>>>(ei, E, N, rowstart, rank,
                                                          csr_src, fillB,
                                                          (const unsigned*)h1, asrc1, adst1,
                                                          es1, ed1);

    // layer 1 aggregation (grouped, 4-edge ILP)
    aggregate1_kernel<<<nwb4, 256, 0, stream>>>((const unsigned*)h1, es1, ed1,
                                                rowstart, csr_src, b1, x2p, N);

    // layer 2
    gemm2_kernel<<<nblk16, 256, 0, stream>>>(x2p, Wb2, h2, N);
    escore2_kernel<<<nwb2, 256, 0, stream>>>((const unsigned*)h2, asrc2, adst2, es2, ed2, N);
    aggregate2_kernel<<<nwb4, 256, 0, stream>>>((const unsigned*)h2, es2, ed2,
                                                rowstart, csr_src, b2, out, N);
}

// Round 12
// 266.805 us; speedup vs baseline: 1.0836x; 1.0836x over previous
//
#include <hip/hip_runtime.h>
#include <hip/hip_bf16.h>

typedef short bf16x8 __attribute__((ext_vector_type(8)));
typedef float f32x4 __attribute__((ext_vector_type(4)));

// --- bf16 pack helpers (RNE) ----------------------------------------------
__device__ __forceinline__ unsigned pack_bf16x2(float lo, float hi) {
    unsigned a = __builtin_bit_cast(unsigned, lo);
    unsigned b = __builtin_bit_cast(unsigned, hi);
    a += 0x7fffu + ((a >> 16) & 1u);
    b += 0x7fffu + ((b >> 16) & 1u);
    return (a >> 16) | (b & 0xffff0000u);
}
__device__ __forceinline__ unsigned short bf16r(float f) {
    unsigned a = __builtin_bit_cast(unsigned, f);
    a += 0x7fffu + ((a >> 16) & 1u);
    return (unsigned short)(a >> 16);
}
__device__ __forceinline__ float bf_lo(unsigned u) {
    return __builtin_bit_cast(float, u << 16);
}
__device__ __forceinline__ float bf_hi(unsigned u) {
    return __builtin_bit_cast(float, u & 0xffff0000u);
}

// ---------------------------------------------------------------------------
// prep: pack W1/W2 into MFMA-B frag-linear bf16 layout.
// ---------------------------------------------------------------------------
__global__ void prep_kernel(const float* __restrict__ W1, const float* __restrict__ W2,
                            unsigned* __restrict__ Wb1, unsigned* __restrict__ Wb2) {
    const int t = blockIdx.x * 256 + threadIdx.x;
    if (t < 2048) {
        const int lane = t & 63, kt = (t >> 6) & 3, ct = t >> 8;
        const int col = ct * 16 + (lane & 15);
        const int kb = 8 * (lane >> 4) + 32 * kt;
        uint4 u;
        u.x = pack_bf16x2(W1[(size_t)(kb + 0) * 128 + col], W1[(size_t)(kb + 1) * 128 + col]);
        u.y = pack_bf16x2(W1[(size_t)(kb + 2) * 128 + col], W1[(size_t)(kb + 3) * 128 + col]);
        u.z = pack_bf16x2(W1[(size_t)(kb + 4) * 128 + col], W1[(size_t)(kb + 5) * 128 + col]);
        u.w = pack_bf16x2(W1[(size_t)(kb + 6) * 128 + col], W1[(size_t)(kb + 7) * 128 + col]);
        *(uint4*)&Wb1[t * 4] = u;
    } else if (t < 3072) {
        const int s = t - 2048;
        const int lane = s & 63, kt = (s >> 6) & 3, ct = s >> 8;
        const int col = ct * 16 + (lane & 15);
        const int kb = 8 * (lane >> 4) + 32 * kt;
        uint4 u;
        u.x = pack_bf16x2(W2[(size_t)(kb + 0) * 64 + col], W2[(size_t)(kb + 1) * 64 + col]);
        u.y = pack_bf16x2(W2[(size_t)(kb + 2) * 64 + col], W2[(size_t)(kb + 3) * 64 + col]);
        u.z = pack_bf16x2(W2[(size_t)(kb + 4) * 64 + col], W2[(size_t)(kb + 5) * 64 + col]);
        u.w = pack_bf16x2(W2[(size_t)(kb + 6) * 64 + col], W2[(size_t)(kb + 7) * 64 + col]);
        *(uint4*)&Wb2[s * 4] = u;
    }
}

// ---------------------------------------------------------------------------
// GEMM1, MFMA: h1[N][128] bf16 = bf16(x) @ bf16(W1).  Wave = 16 rows.
// ---------------------------------------------------------------------------
__global__ __launch_bounds__(256) void gemm1_kernel(const float* __restrict__ x,
                                                    const unsigned* __restrict__ Wb1,
                                                    unsigned short* __restrict__ h1,
                                                    int N) {
    const int wid = threadIdx.x >> 6, lane = threadIdx.x & 63;
    const int row0 = (blockIdx.x * 4 + wid) * 16;
    if (row0 >= N) return;
    const int g = lane >> 4;
    const int mrow = min(row0 + (lane & 15), N - 1);

    bf16x8 afrag[4];
#pragma unroll
    for (int kt = 0; kt < 4; ++kt) {
        const float4 v0 = *(const float4*)&x[(size_t)mrow * 128 + g * 8 + kt * 32];
        const float4 v1 = *(const float4*)&x[(size_t)mrow * 128 + g * 8 + kt * 32 + 4];
        uint4 u;
        u.x = pack_bf16x2(v0.x, v0.y);
        u.y = pack_bf16x2(v0.z, v0.w);
        u.z = pack_bf16x2(v1.x, v1.y);
        u.w = pack_bf16x2(v1.z, v1.w);
        afrag[kt] = __builtin_bit_cast(bf16x8, u);
    }
#pragma unroll
    for (int ct = 0; ct < 8; ++ct) {
        f32x4 acc = {0.f, 0.f, 0.f, 0.f};
#pragma unroll
        for (int kt = 0; kt < 4; ++kt) {
            const bf16x8 b = __builtin_bit_cast(bf16x8, *(const uint4*)&Wb1[((ct * 4 + kt) * 64 + lane) * 4]);
            acc = __builtin_amdgcn_mfma_f32_16x16x32_bf16(afrag[kt], b, acc, 0, 0, 0);
        }
        const int col = ct * 16 + (lane & 15);
#pragma unroll
        for (int r = 0; r < 4; ++r) {
            const int row = row0 + g * 4 + r;
            if (row < N) h1[(size_t)row * 128 + col] = bf16r(acc[r]);
        }
    }
}

// ---------------------------------------------------------------------------
// GEMM2, MFMA: h2[N][64] bf16 = x2(bf16) @ bf16(W2).
// ---------------------------------------------------------------------------
__global__ __launch_bounds__(256) void gemm2_kernel(const unsigned* __restrict__ x2p,
                                                    const unsigned* __restrict__ Wb2,
                                                    unsigned short* __restrict__ h2,
                                                    int N) {
    const int wid = threadIdx.x >> 6, lane = threadIdx.x & 63;
    const int row0 = (blockIdx.x * 4 + wid) * 16;
    if (row0 >= N) return;
    const int g = lane >> 4;
    const int mrow = min(row0 + (lane & 15), N - 1);

    bf16x8 afrag[4];
#pragma unroll
    for (int kt = 0; kt < 4; ++kt)
        afrag[kt] = __builtin_bit_cast(bf16x8, *(const uint4*)&x2p[(size_t)mrow * 64 + g * 4 + kt * 16]);
#pragma unroll
    for (int ct = 0; ct < 4; ++ct) {
        f32x4 acc = {0.f, 0.f, 0.f, 0.f};
#pragma unroll
        for (int kt = 0; kt < 4; ++kt) {
            const bf16x8 b = __builtin_bit_cast(bf16x8, *(const uint4*)&Wb2[((ct * 4 + kt) * 64 + lane) * 4]);
            acc = __builtin_amdgcn_mfma_f32_16x16x32_bf16(afrag[kt], b, acc, 0, 0, 0);
        }
        const int col = ct * 16 + (lane & 15);
#pragma unroll
        for (int r = 0; r < 4; ++r) {
            const int row = row0 + g * 4 + r;
            if (row < N) h2[(size_t)row * 64 + col] = bf16r(acc[r]);
        }
    }
}

// ---------------------------------------------------------------------------
// Scores layer 1: 2 nodes per wave (32 lanes each; lane covers 4 channels).
// ---------------------------------------------------------------------------
__global__ __launch_bounds__(256) void escore1_kernel(const unsigned* __restrict__ h1u,
                                                      const float* __restrict__ asrc,
                                                      const float* __restrict__ adst,
                                                      float* __restrict__ es,
                                                      float* __restrict__ ed, int N) {
    const int lane = threadIdx.x & 63;
    const int n = ((blockIdx.x * 256 + threadIdx.x) >> 6) * 2 + (lane >> 5);
    if (n >= N) return;
    const int c = lane & 31;
    const uint2 u = *(const uint2*)&h1u[(size_t)n * 64 + c * 2];
    const float4 av = *(const float4*)&asrc[c * 4];
    const float4 dv = *(const float4*)&adst[c * 4];
    const float v0 = bf_lo(u.x), v1 = bf_hi(u.x), v2 = bf_lo(u.y), v3 = bf_hi(u.y);
    float s = v0 * av.x + v1 * av.y + v2 * av.z + v3 * av.w;
    float d = v0 * dv.x + v1 * dv.y + v2 * dv.z + v3 * dv.w;
#pragma unroll
    for (int off = 1; off <= 4; off <<= 1) {
        s += __shfl_xor(s, off);
        d += __shfl_xor(d, off);
    }
    if ((c & 7) == 0) {
        es[n * 4 + (c >> 3)] = s;
        ed[n * 4 + (c >> 3)] = d;
    }
}

// Scores layer 2: single head over 64 ch; TWO nodes per wave (32 lanes each).
__global__ __launch_bounds__(256) void escore2_kernel(const unsigned* __restrict__ h2u,
                                                      const float* __restrict__ asrc,
                                                      const float* __restrict__ adst,
                                                      float* __restrict__ es,
                                                      float* __restrict__ ed, int N) {
    const int lane = threadIdx.x & 63;
    const int n = ((blockIdx.x * 256 + threadIdx.x) >> 6) * 2 + (lane >> 5);
    if (n >= N) return;
    const int c = lane & 31;
    const unsigned u = h2u[(size_t)n * 32 + c];
    const float lo = bf_lo(u), hi = bf_hi(u);
    float s = lo * asrc[2 * c] + hi * asrc[2 * c + 1];
    float d = lo * adst[2 * c] + hi * adst[2 * c + 1];
#pragma unroll
    for (int off = 1; off <= 16; off <<= 1) {
        s += __shfl_xor(s, off);
        d += __shfl_xor(d, off);
    }
    if (c == 0) { es[n] = s; ed[n] = d; }
}

// ---------------------------------------------------------------------------
// rank_count: one returning atomic per edge, 8 independent atomics in flight.
// STANDALONE — round-11's block-split fusion with gemm1 regressed (the GEMM
// stream degraded fabric-level atomic latency for the whole dispatch).
// ---------------------------------------------------------------------------
__global__ __launch_bounds__(256) void rank_count_kernel(const int* __restrict__ ei, int E,
                                                         int* __restrict__ deg,
                                                         int* __restrict__ rank) {
    const int stride = gridDim.x * 256;
    int e = blockIdx.x * 256 + threadIdx.x;
    for (; e + 7 * stride < E; e += 8 * stride) {
        int d[8], r[8];
#pragma unroll
        for (int i = 0; i < 8; ++i) d[i] = ei[E + e + i * stride];
#pragma unroll
        for (int i = 0; i < 8; ++i) r[i] = atomicAdd(&deg[d[i]], 1);
#pragma unroll
        for (int i = 0; i < 8; ++i) rank[e + i * stride] = r[i];
    }
    for (; e < E; e += stride)
        rank[e] = atomicAdd(&deg[ei[E + e]], 1);
}

// ---------------------------------------------------------------------------
// CSR scan: exclusive scan of (deg+1); self-loop takes LAST slot per segment.
// ---------------------------------------------------------------------------
__global__ __launch_bounds__(256) void scan_p1_kernel(const int* __restrict__ deg,
                                                      int* __restrict__ excl,
                                                      int* __restrict__ bsum, int N) {
    __shared__ int lds[256];
    const int tid = threadIdx.x;
    const int base = blockIdx.x * 2048;
    const int idx0 = base + tid * 8;
    int v[8];
    int s = 0;
#pragma unroll
    for (int i = 0; i < 8; ++i) {
        v[i] = (idx0 + i < N) ? deg[idx0 + i] + 1 : 0;  // +1 = self-loop
        s += v[i];
    }
    lds[tid] = s;
    __syncthreads();
    for (int off = 1; off < 256; off <<= 1) {
        int t = (tid >= off) ? lds[tid - off] : 0;
        __syncthreads();
        lds[tid] += t;
        __syncthreads();
    }
    const int texcl = lds[tid] - s;
    if (tid == 255) bsum[blockIdx.x] = lds[255];
    int run = texcl;
#pragma unroll
    for (int i = 0; i < 8; ++i) {
        if (idx0 + i < N) excl[idx0 + i] = run;
        run += v[i];
    }
}

__global__ void scan_p2_kernel(int* __restrict__ bsum, int nchunks) {
    const int lane = threadIdx.x;
    int v = (lane < nchunks) ? bsum[lane] : 0;
    const int orig = v;
#pragma unroll
    for (int off = 1; off < 64; off <<= 1) {
        int t = __shfl_up(v, off);
        if (lane >= off) v += t;
    }
    if (lane < nchunks) bsum[lane] = v - orig;
}

__global__ void scan_p3_kernel(const int* __restrict__ excl, const int* __restrict__ bsum,
                               int* __restrict__ rowstart, int N, int Etot) {
    const int i = blockIdx.x * 256 + threadIdx.x;
    if (i < N) rowstart[i] = excl[i] + bsum[i >> 11];
    if (i == 0) rowstart[N] = Etot;
}

__global__ void csr_fill_kernel(const int* __restrict__ ei, int E, int N,
                                const int* __restrict__ rowstart,
                                const int* __restrict__ rank,
                                int* __restrict__ csr_src) {
    const int e = blockIdx.x * 256 + threadIdx.x;
    if (e < E) {
        const int d = ei[E + e];
        csr_src[rowstart[d] + rank[e]] = ei[e];
    } else if (e < E + N) {
        const int d = e - E;
        csr_src[rowstart[d + 1] - 1] = d;
    }
}

// ---------------------------------------------------------------------------
// Aggregation layer 1, GROUPED: 4 nodes/wave, 16 lanes/node, lane = 8 ch
// (uint4 gather).  4-edge unroll -> 4 outstanding gathers per lane.
// Invalid slots get p=0 (branch-free).
// ---------------------------------------------------------------------------
__global__ __launch_bounds__(256) void aggregate1_kernel(const unsigned* __restrict__ h1p,
                                                         const float* __restrict__ es,
                                                         const float* __restrict__ ed,
                                                         const int* __restrict__ rowstart,
                                                         const int* __restrict__ csr_src,
                                                         const float* __restrict__ b,
                                                         unsigned* __restrict__ x2p, int N) {
    const int lane = threadIdx.x & 63;
    const int w = (blockIdx.x * 256 + threadIdx.x) >> 6;
    const int l16 = lane & 15;
    const int n = w * 4 + (lane >> 4);
    const int hh = l16 >> 2;  // head 0..3
    const bool valid = n < N;
    const int nc = valid ? n : N - 1;
    const int beg = rowstart[nc];
    const int deg = valid ? rowstart[nc + 1] - beg : 0;
    const float edv = ed[nc * 4 + hh];

    int dmax = deg;
    dmax = max(dmax, __shfl_xor(dmax, 16));
    dmax = max(dmax, __shfl_xor(dmax, 32));

    float acc0 = 0.f, acc1 = 0.f, acc2 = 0.f, acc3 = 0.f;
    float acc4 = 0.f, acc5 = 0.f, acc6 = 0.f, acc7 = 0.f;
    float den = 0.f;
    for (int j = 0; j < dmax; j += 4) {
        const bool va = j < deg, vb = j + 1 < deg, vc = j + 2 < deg, vd = j + 3 < deg;
        const int pa_ = va ? beg + j : 0;
        const int pb_ = vb ? beg + j + 1 : 0;
        const int pc_ = vc ? beg + j + 2 : 0;
        const int pd_ = vd ? beg + j + 3 : 0;
        const int sa = csr_src[pa_];
        const int sb = csr_src[pb_];
        const int sc = csr_src[pc_];
        const int sd = csr_src[pd_];
        const uint4 ua = *(const uint4*)&h1p[(size_t)sa * 64 + l16 * 4];
        const uint4 ub = *(const uint4*)&h1p[(size_t)sb * 64 + l16 * 4];
        const uint4 uc = *(const uint4*)&h1p[(size_t)sc * 64 + l16 * 4];
        const uint4 ud = *(const uint4*)&h1p[(size_t)sd * 64 + l16 * 4];
        const float xa = es[sa * 4 + hh] + edv;
        const float xb = es[sb * 4 + hh] + edv;
        const float xc = es[sc * 4 + hh] + edv;
        const float xd = es[sd * 4 + hh] + edv;
        float qa = __expf(fmaxf(xa, 0.2f * xa));
        float qb = __expf(fmaxf(xb, 0.2f * xb));
        float qc = __expf(fmaxf(xc, 0.2f * xc));
        float qd = __expf(fmaxf(xd, 0.2f * xd));
        qa = va ? qa : 0.f;
        qb = vb ? qb : 0.f;
        qc = vc ? qc : 0.f;
        qd = vd ? qd : 0.f;
        den += (qa + qb) + (qc + qd);
        acc0 = fmaf(qa, bf_lo(ua.x), fmaf(qb, bf_lo(ub.x), fmaf(qc, bf_lo(uc.x), fmaf(qd, bf_lo(ud.x), acc0))));
        acc1 = fmaf(qa, bf_hi(ua.x), fmaf(qb, bf_hi(ub.x), fmaf(qc, bf_hi(uc.x), fmaf(qd, bf_hi(ud.x), acc1))));
        acc2 = fmaf(qa, bf_lo(ua.y), fmaf(qb, bf_lo(ub.y), fmaf(qc, bf_lo(uc.y), fmaf(qd, bf_lo(ud.y), acc2))));
        acc3 = fmaf(qa, bf_hi(ua.y), fmaf(qb, bf_hi(ub.y), fmaf(qc, bf_hi(uc.y), fmaf(qd, bf_hi(ud.y), acc3))));
        acc4 = fmaf(qa, bf_lo(ua.z), fmaf(qb, bf_lo(ub.z), fmaf(qc, bf_lo(uc.z), fmaf(qd, bf_lo(ud.z), acc4))));
        acc5 = fmaf(qa, bf_hi(ua.z), fmaf(qb, bf_hi(ub.z), fmaf(qc, bf_hi(uc.z), fmaf(qd, bf_hi(ud.z), acc5))));
        acc6 = fmaf(qa, bf_lo(ua.w), fmaf(qb, bf_lo(ub.w), fmaf(qc, bf_lo(uc.w), fmaf(qd, bf_lo(ud.w), acc6))));
        acc7 = fmaf(qa, bf_hi(ua.w), fmaf(qb, bf_hi(ub.w), fmaf(qc, bf_hi(uc.w), fmaf(qd, bf_hi(ud.w), acc7))));
    }
    if (valid) {
        const float inv = __builtin_amdgcn_rcpf(den);
        const float4 ba = *(const float4*)&b[l16 * 8];
        const float4 bb = *(const float4*)&b[l16 * 8 + 4];
        float o0 = fmaf(acc0, inv, ba.x); o0 = fmaxf(o0, 0.01f * o0);
        float o1 = fmaf(acc1, inv, ba.y); o1 = fmaxf(o1, 0.01f * o1);
        float o2 = fmaf(acc2, inv, ba.z); o2 = fmaxf(o2, 0.01f * o2);
        float o3 = fmaf(acc3, inv, ba.w); o3 = fmaxf(o3, 0.01f * o3);
        float o4 = fmaf(acc4, inv, bb.x); o4 = fmaxf(o4, 0.01f * o4);
        float o5 = fmaf(acc5, inv, bb.y); o5 = fmaxf(o5, 0.01f * o5);
        float o6 = fmaf(acc6, inv, bb.z); o6 = fmaxf(o6, 0.01f * o6);
        float o7 = fmaf(acc7, inv, bb.w); o7 = fmaxf(o7, 0.01f * o7);
        uint4 o;
        o.x = pack_bf16x2(o0, o1);
        o.y = pack_bf16x2(o2, o3);
        o.z = pack_bf16x2(o4, o5);
        o.w = pack_bf16x2(o6, o7);
        *(uint4*)&x2p[(size_t)n * 64 + l16 * 4] = o;
    }
}

// ---------------------------------------------------------------------------
// Aggregation layer 2, GROUPED: 4 nodes/wave, 16 lanes/node, lane = 4 ch
// (uint2 gather).  Single head.  4-edge unroll.
// ---------------------------------------------------------------------------
__global__ __launch_bounds__(256) void aggregate2_kernel(const unsigned* __restrict__ h2p,
                                                         const float* __restrict__ es,
                                                         const float* __restrict__ ed,
                                                         const int* __restrict__ rowstart,
                                                         const int* __restrict__ csr_src,
                                                         const float* __restrict__ b,
                                                         float* __restrict__ out, int N) {
    const int lane = threadIdx.x & 63;
    const int w = (blockIdx.x * 256 + threadIdx.x) >> 6;
    const int l16 = lane & 15;
    const int n = w * 4 + (lane >> 4);
    const bool valid = n < N;
    const int nc = valid ? n : N - 1;
    const int beg = rowstart[nc];
    const int deg = valid ? rowstart[nc + 1] - beg : 0;
    const float edv = ed[nc];

    int dmax = deg;
    dmax = max(dmax, __shfl_xor(dmax, 16));
    dmax = max(dmax, __shfl_xor(dmax, 32));

    float acc0 = 0.f, acc1 = 0.f, acc2 = 0.f, acc3 = 0.f;
    float den = 0.f;
    for (int j = 0; j < dmax; j += 4) {
        const bool va = j < deg, vb = j + 1 < deg, vc = j + 2 < deg, vd = j + 3 < deg;
        const int pa_ = va ? beg + j : 0;
        const int pb_ = vb ? beg + j + 1 : 0;
        const int pc_ = vc ? beg + j + 2 : 0;
        const int pd_ = vd ? beg + j + 3 : 0;
        const int sa = csr_src[pa_];
        const int sb = csr_src[pb_];
        const int sc = csr_src[pc_];
        const int sd = csr_src[pd_];
        const uint2 ua = *(const uint2*)&h2p[(size_t)sa * 32 + l16 * 2];
        const uint2 ub = *(const uint2*)&h2p[(size_t)sb * 32 + l16 * 2];
        const uint2 uc = *(const uint2*)&h2p[(size_t)sc * 32 + l16 * 2];
        const uint2 ud = *(const uint2*)&h2p[(size_t)sd * 32 + l16 * 2];
        const float xa = es[sa] + edv;
        const float xb = es[sb] + edv;
        const float xc = es[sc] + edv;
        const float xd = es[sd] + edv;
        float qa = __expf(fmaxf(xa, 0.2f * xa));
        float qb = __expf(fmaxf(xb, 0.2f * xb));
        float qc = __expf(fmaxf(xc, 0.2f * xc));
        float qd = __expf(fmaxf(xd, 0.2f * xd));
        qa = va ? qa : 0.f;
        qb = vb ? qb : 0.f;
        qc = vc ? qc : 0.f;
        qd = vd ? qd : 0.f;
        den += (qa + qb) + (qc + qd);
        acc0 = fmaf(qa, bf_lo(ua.x), fmaf(qb, bf_lo(ub.x), fmaf(qc, bf_lo(uc.x), fmaf(qd, bf_lo(ud.x), acc0))));
        acc1 = fmaf(qa, bf_hi(ua.x), fmaf(qb, bf_hi(ub.x), fmaf(qc, bf_hi(uc.x), fmaf(qd, bf_hi(ud.x), acc1))));
        acc2 = fmaf(qa, bf_lo(ua.y), fmaf(qb, bf_lo(ub.y), fmaf(qc, bf_lo(uc.y), fmaf(qd, bf_lo(ud.y), acc2))));
        acc3 = fmaf(qa, bf_hi(ua.y), fmaf(qb, bf_hi(ub.y), fmaf(qc, bf_hi(uc.y), fmaf(qd, bf_hi(ud.y), acc3))));
    }
    if (valid) {
        const float inv = __builtin_amdgcn_rcpf(den);
        const float4 bv = *(const float4*)&b[l16 * 4];
        float4 o;
        o.x = fmaf(acc0, inv, bv.x);
        o.y = fmaf(acc1, inv, bv.y);
        o.z = fmaf(acc2, inv, bv.z);
        o.w = fmaf(acc3, inv, bv.w);
        *(float4*)&out[(size_t)n * 64 + l16 * 4] = o;
    }
}

// ---------------------------------------------------------------------------
extern "C" void kernel_launch(void* const* d_in, const int* in_sizes, int n_in,
                              void* d_out, int out_size, void* d_ws, size_t ws_size,
                              hipStream_t stream) {
    const float* x     = (const float*)d_in[0];
    const int*   ei    = (const int*)d_in[1];
    const float* W1    = (const float*)d_in[2];
    const float* asrc1 = (const float*)d_in[3];
    const float* adst1 = (const float*)d_in[4];
    const float* b1    = (const float*)d_in[5];
    const float* W2    = (const float*)d_in[6];
    const float* asrc2 = (const float*)d_in[7];
    const float* adst2 = (const float*)d_in[8];
    const float* b2    = (const float*)d_in[9];
    float* out = (float*)d_out;

    const int N = in_sizes[0] / 128;
    const int E = in_sizes[1] / 2;
    const int Etot = E + N;

    // workspace layout (~83 MB)
    char* p = (char*)d_ws;
    auto alloc = [&](size_t bytes) {
        char* q = p;
        p += (bytes + 255) & ~size_t(255);
        return q;
    };
    unsigned short* h1 = (unsigned short*)alloc((size_t)N * 128 * 2);  // bf16 h1
    unsigned* x2p      = (unsigned*)alloc((size_t)N * 64 * 4);         // bf16x2 x2
    unsigned short* h2 = (unsigned short*)alloc((size_t)N * 64 * 2);   // bf16 h2
    float* es1      = (float*)alloc((size_t)N * 4 * 4);
    float* ed1      = (float*)alloc((size_t)N * 4 * 4);
    float* es2      = (float*)alloc((size_t)N * 4);
    float* ed2      = (float*)alloc((size_t)N * 4);
    int*   deg      = (int*)alloc((size_t)N * 4);
    int*   excl     = (int*)alloc((size_t)N * 4);
    int*   bsum     = (int*)alloc(1024);
    int*   rowstart = (int*)alloc((size_t)(N + 1) * 4);
    int*   rank     = (int*)alloc((size_t)E * 4);
    int*   csr_src  = (int*)alloc((size_t)Etot * 4);
    unsigned* Wb1   = (unsigned*)alloc(2048 * 16);
    unsigned* Wb2   = (unsigned*)alloc(1024 * 16);

    const int nblk16 = (N + 63) / 64;       // MFMA gemms: 4 waves x 16 rows
    const int nwb2 = (N / 2 + 3) / 4 + 1;   // 2-nodes-per-wave kernels
    const int nwb4 = (N + 15) / 16;         // 4-nodes-per-wave agg kernels
    const int nchunks = (N + 2047) / 2048;  // <= 64 required (N <= 131072)

    // weight prep + degree init
    prep_kernel<<<12, 256, 0, stream>>>(W1, W2, Wb1, Wb2);
    hipMemsetAsync(deg, 0, (size_t)N * 4, stream);

    // layer 1 projection (MFMA) + scores
    gemm1_kernel<<<nblk16, 256, 0, stream>>>(x, Wb1, h1, N);
    escore1_kernel<<<nwb2, 256, 0, stream>>>((const unsigned*)h1, asrc1, adst1, es1, ed1, N);

    // CSR by destination (shared by both layers)
    rank_count_kernel<<<512, 256, 0, stream>>>(ei, E, deg, rank);
    scan_p1_kernel<<<nchunks, 256, 0, stream>>>(deg, excl, bsum, N);
    scan_p2_kernel<<<1, 64, 0, stream>>>(bsum, nchunks);
    scan_p3_kernel<<<(N + 255) / 256, 256, 0, stream>>>(excl, bsum, rowstart, N, Etot);
    csr_fill_kernel<<<(Etot + 255) / 256, 256, 0, stream>>>(ei, E, N, rowstart, rank, csr_src);

    // layer 1 aggregation (grouped, 4-edge ILP)
    aggregate1_kernel<<<nwb4, 256, 0, stream>>>((const unsigned*)h1, es1, ed1,
                                                rowstart, csr_src, b1, x2p, N);

    // layer 2
    gemm2_kernel<<<nblk16, 256, 0, stream>>>(x2p, Wb2, h2, N);
    escore2_kernel<<<nwb2, 256, 0, stream>>>((const unsigned*)h2, asrc2, adst2, es2, ed2, N);
    aggregate2_kernel<<<nwb4, 256, 0, stream>>>((const unsigned*)h2, es2, ed2,
                                                rowstart, csr_src, b2, out, N);
}

// Round 13
// 258.208 us; speedup vs baseline: 1.1197x; 1.0333x over previous
//
#include <hip/hip_runtime.h>
#include <hip/hip_bf16.h>

typedef short bf16x8 __attribute__((ext_vector_type(8)));
typedef float f32x4 __attribute__((ext_vector_type(4)));

// --- bf16 pack helpers (RNE) ----------------------------------------------
__device__ __forceinline__ unsigned pack_bf16x2(float lo, float hi) {
    unsigned a = __builtin_bit_cast(unsigned, lo);
    unsigned b = __builtin_bit_cast(unsigned, hi);
    a += 0x7fffu + ((a >> 16) & 1u);
    b += 0x7fffu + ((b >> 16) & 1u);
    return (a >> 16) | (b & 0xffff0000u);
}
__device__ __forceinline__ unsigned short bf16r(float f) {
    unsigned a = __builtin_bit_cast(unsigned, f);
    a += 0x7fffu + ((a >> 16) & 1u);
    return (unsigned short)(a >> 16);
}
__device__ __forceinline__ float bf_lo(unsigned u) {
    return __builtin_bit_cast(float, u << 16);
}
__device__ __forceinline__ float bf_hi(unsigned u) {
    return __builtin_bit_cast(float, u & 0xffff0000u);
}

// ---------------------------------------------------------------------------
// prep: pack W1/W2 into MFMA-B frag-linear bf16 layout + zero deg[] (the
// deg memset folded in; removes one dispatch).
// ---------------------------------------------------------------------------
__global__ void prep_kernel(const float* __restrict__ W1, const float* __restrict__ W2,
                            unsigned* __restrict__ Wb1, unsigned* __restrict__ Wb2,
                            int* __restrict__ deg, int N) {
    const int t = blockIdx.x * 256 + threadIdx.x;
    if (t < 2048) {
        const int lane = t & 63, kt = (t >> 6) & 3, ct = t >> 8;
        const int col = ct * 16 + (lane & 15);
        const int kb = 8 * (lane >> 4) + 32 * kt;
        uint4 u;
        u.x = pack_bf16x2(W1[(size_t)(kb + 0) * 128 + col], W1[(size_t)(kb + 1) * 128 + col]);
        u.y = pack_bf16x2(W1[(size_t)(kb + 2) * 128 + col], W1[(size_t)(kb + 3) * 128 + col]);
        u.z = pack_bf16x2(W1[(size_t)(kb + 4) * 128 + col], W1[(size_t)(kb + 5) * 128 + col]);
        u.w = pack_bf16x2(W1[(size_t)(kb + 6) * 128 + col], W1[(size_t)(kb + 7) * 128 + col]);
        *(uint4*)&Wb1[t * 4] = u;
    } else if (t < 3072) {
        const int s = t - 2048;
        const int lane = s & 63, kt = (s >> 6) & 3, ct = s >> 8;
        const int col = ct * 16 + (lane & 15);
        const int kb = 8 * (lane >> 4) + 32 * kt;
        uint4 u;
        u.x = pack_bf16x2(W2[(size_t)(kb + 0) * 64 + col], W2[(size_t)(kb + 1) * 64 + col]);
        u.y = pack_bf16x2(W2[(size_t)(kb + 2) * 64 + col], W2[(size_t)(kb + 3) * 64 + col]);
        u.z = pack_bf16x2(W2[(size_t)(kb + 4) * 64 + col], W2[(size_t)(kb + 5) * 64 + col]);
        u.w = pack_bf16x2(W2[(size_t)(kb + 6) * 64 + col], W2[(size_t)(kb + 7) * 64 + col]);
        *(uint4*)&Wb2[s * 4] = u;
    }
    for (int i = t; i < N; i += gridDim.x * 256) deg[i] = 0;
}

// ---------------------------------------------------------------------------
// GEMM1 + FUSED scores.  h1[N][128] bf16 = bf16(x) @ bf16(W1); es/ed[N][4]
// from fp32 accumulators.  Head = ct>>1 is uniform per ct-tile, so per-head
// score partials accumulate with static indexing during the ct loop; 4-step
// shfl_xor reduce over the 16-lane row group at the end.  Wave = 16 rows.
// ---------------------------------------------------------------------------
__global__ __launch_bounds__(256) void gemm1_kernel(const float* __restrict__ x,
                                                    const unsigned* __restrict__ Wb1,
                                                    const float* __restrict__ asrc,
                                                    const float* __restrict__ adst,
                                                    unsigned short* __restrict__ h1,
                                                    float* __restrict__ es,
                                                    float* __restrict__ ed,
                                                    int N) {
    const int wid = threadIdx.x >> 6, lane = threadIdx.x & 63;
    const int row0 = (blockIdx.x * 4 + wid) * 16;
    if (row0 >= N) return;
    const int g = lane >> 4, l16 = lane & 15;
    const int mrow = min(row0 + l16, N - 1);

    bf16x8 afrag[4];
#pragma unroll
    for (int kt = 0; kt < 4; ++kt) {
        const float4 v0 = *(const float4*)&x[(size_t)mrow * 128 + g * 8 + kt * 32];
        const float4 v1 = *(const float4*)&x[(size_t)mrow * 128 + g * 8 + kt * 32 + 4];
        uint4 u;
        u.x = pack_bf16x2(v0.x, v0.y);
        u.y = pack_bf16x2(v0.z, v0.w);
        u.z = pack_bf16x2(v1.x, v1.y);
        u.w = pack_bf16x2(v1.z, v1.w);
        afrag[kt] = __builtin_bit_cast(bf16x8, u);
    }
    float psh[4][4] = {};  // [head][row]
    float pdh[4][4] = {};
#pragma unroll
    for (int ct = 0; ct < 8; ++ct) {
        f32x4 acc = {0.f, 0.f, 0.f, 0.f};
#pragma unroll
        for (int kt = 0; kt < 4; ++kt) {
            const bf16x8 b = __builtin_bit_cast(bf16x8, *(const uint4*)&Wb1[((ct * 4 + kt) * 64 + lane) * 4]);
            acc = __builtin_amdgcn_mfma_f32_16x16x32_bf16(afrag[kt], b, acc, 0, 0, 0);
        }
        const int col = ct * 16 + l16;
        const float as_ = asrc[col], ad_ = adst[col];
        const int hh = ct >> 1;
#pragma unroll
        for (int r = 0; r < 4; ++r) {
            psh[hh][r] = fmaf(acc[r], as_, psh[hh][r]);
            pdh[hh][r] = fmaf(acc[r], ad_, pdh[hh][r]);
        }
#pragma unroll
        for (int r = 0; r < 4; ++r) {
            const int row = row0 + g * 4 + r;
            if (row < N) h1[(size_t)row * 128 + col] = bf16r(acc[r]);
        }
    }
    // reduce score partials over the 16 lanes of each row group
#pragma unroll
    for (int hh = 0; hh < 4; ++hh)
#pragma unroll
        for (int r = 0; r < 4; ++r) {
#pragma unroll
            for (int off = 1; off <= 8; off <<= 1) {
                psh[hh][r] += __shfl_xor(psh[hh][r], off);
                pdh[hh][r] += __shfl_xor(pdh[hh][r], off);
            }
        }
    if (l16 == 0) {
#pragma unroll
        for (int r = 0; r < 4; ++r) {
            const int row = row0 + g * 4 + r;
            if (row < N) {
#pragma unroll
                for (int hh = 0; hh < 4; ++hh) {
                    es[row * 4 + hh] = psh[hh][r];
                    ed[row * 4 + hh] = pdh[hh][r];
                }
            }
        }
    }
}

// ---------------------------------------------------------------------------
// GEMM2 + FUSED scores (single head): h2[N][64] bf16 = x2(bf16) @ bf16(W2);
// es2/ed2[N] fp32 from accumulators, 16-lane reduce.
// ---------------------------------------------------------------------------
__global__ __launch_bounds__(256) void gemm2_kernel(const unsigned* __restrict__ x2p,
                                                    const unsigned* __restrict__ Wb2,
                                                    const float* __restrict__ asrc,
                                                    const float* __restrict__ adst,
                                                    unsigned short* __restrict__ h2,
                                                    float* __restrict__ es,
                                                    float* __restrict__ ed,
                                                    int N) {
    const int wid = threadIdx.x >> 6, lane = threadIdx.x & 63;
    const int row0 = (blockIdx.x * 4 + wid) * 16;
    if (row0 >= N) return;
    const int g = lane >> 4, l16 = lane & 15;
    const int mrow = min(row0 + l16, N - 1);

    bf16x8 afrag[4];
#pragma unroll
    for (int kt = 0; kt < 4; ++kt)
        afrag[kt] = __builtin_bit_cast(bf16x8, *(const uint4*)&x2p[(size_t)mrow * 64 + g * 4 + kt * 16]);
    float ps[4] = {}, pd[4] = {};
#pragma unroll
    for (int ct = 0; ct < 4; ++ct) {
        f32x4 acc = {0.f, 0.f, 0.f, 0.f};
#pragma unroll
        for (int kt = 0; kt < 4; ++kt) {
            const bf16x8 b = __builtin_bit_cast(bf16x8, *(const uint4*)&Wb2[((ct * 4 + kt) * 64 + lane) * 4]);
            acc = __builtin_amdgcn_mfma_f32_16x16x32_bf16(afrag[kt], b, acc, 0, 0, 0);
        }
        const int col = ct * 16 + l16;
        const float as_ = asrc[col], ad_ = adst[col];
#pragma unroll
        for (int r = 0; r < 4; ++r) {
            ps[r] = fmaf(acc[r], as_, ps[r]);
            pd[r] = fmaf(acc[r], ad_, pd[r]);
        }
#pragma unroll
        for (int r = 0; r < 4; ++r) {
            const int row = row0 + g * 4 + r;
            if (row < N) h2[(size_t)row * 64 + col] = bf16r(acc[r]);
        }
    }
#pragma unroll
    for (int r = 0; r < 4; ++r) {
#pragma unroll
        for (int off = 1; off <= 8; off <<= 1) {
            ps[r] += __shfl_xor(ps[r], off);
            pd[r] += __shfl_xor(pd[r], off);
        }
    }
    if (l16 == 0) {
#pragma unroll
        for (int r = 0; r < 4; ++r) {
            const int row = row0 + g * 4 + r;
            if (row < N) { es[row] = ps[r]; ed[row] = pd[r]; }
        }
    }
}

// ---------------------------------------------------------------------------
// rank_count: one returning atomic per edge, 8 independent atomics in flight.
// STANDALONE — block-split fusion with gemm1 regressed (round 11).
// ---------------------------------------------------------------------------
__global__ __launch_bounds__(256) void rank_count_kernel(const int* __restrict__ ei, int E,
                                                         int* __restrict__ deg,
                                                         int* __restrict__ rank) {
    const int stride = gridDim.x * 256;
    int e = blockIdx.x * 256 + threadIdx.x;
    for (; e + 7 * stride < E; e += 8 * stride) {
        int d[8], r[8];
#pragma unroll
        for (int i = 0; i < 8; ++i) d[i] = ei[E + e + i * stride];
#pragma unroll
        for (int i = 0; i < 8; ++i) r[i] = atomicAdd(&deg[d[i]], 1);
#pragma unroll
        for (int i = 0; i < 8; ++i) rank[e + i * stride] = r[i];
    }
    for (; e < E; e += stride)
        rank[e] = atomicAdd(&deg[ei[E + e]], 1);
}

// ---------------------------------------------------------------------------
// CSR scan: exclusive scan of (deg+1); self-loop takes LAST slot per segment.
// ---------------------------------------------------------------------------
__global__ __launch_bounds__(256) void scan_p1_kernel(const int* __restrict__ deg,
                                                      int* __restrict__ excl,
                                                      int* __restrict__ bsum, int N) {
    __shared__ int lds[256];
    const int tid = threadIdx.x;
    const int base = blockIdx.x * 2048;
    const int idx0 = base + tid * 8;
    int v[8];
    int s = 0;
#pragma unroll
    for (int i = 0; i < 8; ++i) {
        v[i] = (idx0 + i < N) ? deg[idx0 + i] + 1 : 0;  // +1 = self-loop
        s += v[i];
    }
    lds[tid] = s;
    __syncthreads();
    for (int off = 1; off < 256; off <<= 1) {
        int t = (tid >= off) ? lds[tid - off] : 0;
        __syncthreads();
        lds[tid] += t;
        __syncthreads();
    }
    const int texcl = lds[tid] - s;
    if (tid == 255) bsum[blockIdx.x] = lds[255];
    int run = texcl;
#pragma unroll
    for (int i = 0; i < 8; ++i) {
        if (idx0 + i < N) excl[idx0 + i] = run;
        run += v[i];
    }
}

__global__ void scan_p2_kernel(int* __restrict__ bsum, int nchunks) {
    const int lane = threadIdx.x;
    int v = (lane < nchunks) ? bsum[lane] : 0;
    const int orig = v;
#pragma unroll
    for (int off = 1; off < 64; off <<= 1) {
        int t = __shfl_up(v, off);
        if (lane >= off) v += t;
    }
    if (lane < nchunks) bsum[lane] = v - orig;
}

__global__ void scan_p3_kernel(const int* __restrict__ excl, const int* __restrict__ bsum,
                               int* __restrict__ rowstart, int N, int Etot) {
    const int i = blockIdx.x * 256 + threadIdx.x;
    if (i < N) rowstart[i] = excl[i] + bsum[i >> 11];
    if (i == 0) rowstart[N] = Etot;
}

__global__ void csr_fill_kernel(const int* __restrict__ ei, int E, int N,
                                const int* __restrict__ rowstart,
                                const int* __restrict__ rank,
                                int* __restrict__ csr_src) {
    const int e = blockIdx.x * 256 + threadIdx.x;
    if (e < E) {
        const int d = ei[E + e];
        csr_src[rowstart[d] + rank[e]] = ei[e];
    } else if (e < E + N) {
        const int d = e - E;
        csr_src[rowstart[d + 1] - 1] = d;
    }
}

// ---------------------------------------------------------------------------
// Aggregation layer 1, GROUPED: 4 nodes/wave, 16 lanes/node, lane = 8 ch
// (uint4 gather).  4-edge unroll; invalid slots get p=0 (branch-free).
// Bandwidth-bound at ~3.6 TB/s of L2-miss gather traffic (round-12 PMC).
// ---------------------------------------------------------------------------
__global__ __launch_bounds__(256) void aggregate1_kernel(const unsigned* __restrict__ h1p,
                                                         const float* __restrict__ es,
                                                         const float* __restrict__ ed,
                                                         const int* __restrict__ rowstart,
                                                         const int* __restrict__ csr_src,
                                                         const float* __restrict__ b,
                                                         unsigned* __restrict__ x2p, int N) {
    const int lane = threadIdx.x & 63;
    const int w = (blockIdx.x * 256 + threadIdx.x) >> 6;
    const int l16 = lane & 15;
    const int n = w * 4 + (lane >> 4);
    const int hh = l16 >> 2;  // head 0..3
    const bool valid = n < N;
    const int nc = valid ? n : N - 1;
    const int beg = rowstart[nc];
    const int deg = valid ? rowstart[nc + 1] - beg : 0;
    const float edv = ed[nc * 4 + hh];

    int dmax = deg;
    dmax = max(dmax, __shfl_xor(dmax, 16));
    dmax = max(dmax, __shfl_xor(dmax, 32));

    float acc0 = 0.f, acc1 = 0.f, acc2 = 0.f, acc3 = 0.f;
    float acc4 = 0.f, acc5 = 0.f, acc6 = 0.f, acc7 = 0.f;
    float den = 0.f;
    for (int j = 0; j < dmax; j += 4) {
        const bool va = j < deg, vb = j + 1 < deg, vc = j + 2 < deg, vd = j + 3 < deg;
        const int pa_ = va ? beg + j : 0;
        const int pb_ = vb ? beg + j + 1 : 0;
        const int pc_ = vc ? beg + j + 2 : 0;
        const int pd_ = vd ? beg + j + 3 : 0;
        const int sa = csr_src[pa_];
        const int sb = csr_src[pb_];
        const int sc = csr_src[pc_];
        const int sd = csr_src[pd_];
        const uint4 ua = *(const uint4*)&h1p[(size_t)sa * 64 + l16 * 4];
        const uint4 ub = *(const uint4*)&h1p[(size_t)sb * 64 + l16 * 4];
        const uint4 uc = *(const uint4*)&h1p[(size_t)sc * 64 + l16 * 4];
        const uint4 ud = *(const uint4*)&h1p[(size_t)sd * 64 + l16 * 4];
        const float xa = es[sa * 4 + hh] + edv;
        const float xb = es[sb * 4 + hh] + edv;
        const float xc = es[sc * 4 + hh] + edv;
        const float xd = es[sd * 4 + hh] + edv;
        float qa = __expf(fmaxf(xa, 0.2f * xa));
        float qb = __expf(fmaxf(xb, 0.2f * xb));
        float qc = __expf(fmaxf(xc, 0.2f * xc));
        float qd = __expf(fmaxf(xd, 0.2f * xd));
        qa = va ? qa : 0.f;
        qb = vb ? qb : 0.f;
        qc = vc ? qc : 0.f;
        qd = vd ? qd : 0.f;
        den += (qa + qb) + (qc + qd);
        acc0 = fmaf(qa, bf_lo(ua.x), fmaf(qb, bf_lo(ub.x), fmaf(qc, bf_lo(uc.x), fmaf(qd, bf_lo(ud.x), acc0))));
        acc1 = fmaf(qa, bf_hi(ua.x), fmaf(qb, bf_hi(ub.x), fmaf(qc, bf_hi(uc.x), fmaf(qd, bf_hi(ud.x), acc1))));
        acc2 = fmaf(qa, bf_lo(ua.y), fmaf(qb, bf_lo(ub.y), fmaf(qc, bf_lo(uc.y), fmaf(qd, bf_lo(ud.y), acc2))));
        acc3 = fmaf(qa, bf_hi(ua.y), fmaf(qb, bf_hi(ub.y), fmaf(qc, bf_hi(uc.y), fmaf(qd, bf_hi(ud.y), acc3))));
        acc4 = fmaf(qa, bf_lo(ua.z), fmaf(qb, bf_lo(ub.z), fmaf(qc, bf_lo(uc.z), fmaf(qd, bf_lo(ud.z), acc4))));
        acc5 = fmaf(qa, bf_hi(ua.z), fmaf(qb, bf_hi(ub.z), fmaf(qc, bf_hi(uc.z), fmaf(qd, bf_hi(ud.z), acc5))));
        acc6 = fmaf(qa, bf_lo(ua.w), fmaf(qb, bf_lo(ub.w), fmaf(qc, bf_lo(uc.w), fmaf(qd, bf_lo(ud.w), acc6))));
        acc7 = fmaf(qa, bf_hi(ua.w), fmaf(qb, bf_hi(ub.w), fmaf(qc, bf_hi(uc.w), fmaf(qd, bf_hi(ud.w), acc7))));
    }
    if (valid) {
        const float inv = __builtin_amdgcn_rcpf(den);
        const float4 ba = *(const float4*)&b[l16 * 8];
        const float4 bb = *(const float4*)&b[l16 * 8 + 4];
        float o0 = fmaf(acc0, inv, ba.x); o0 = fmaxf(o0, 0.01f * o0);
        float o1 = fmaf(acc1, inv, ba.y); o1 = fmaxf(o1, 0.01f * o1);
        float o2 = fmaf(acc2, inv, ba.z); o2 = fmaxf(o2, 0.01f * o2);
        float o3 = fmaf(acc3, inv, ba.w); o3 = fmaxf(o3, 0.01f * o3);
        float o4 = fmaf(acc4, inv, bb.x); o4 = fmaxf(o4, 0.01f * o4);
        float o5 = fmaf(acc5, inv, bb.y); o5 = fmaxf(o5, 0.01f * o5);
        float o6 = fmaf(acc6, inv, bb.z); o6 = fmaxf(o6, 0.01f * o6);
        float o7 = fmaf(acc7, inv, bb.w); o7 = fmaxf(o7, 0.01f * o7);
        uint4 o;
        o.x = pack_bf16x2(o0, o1);
        o.y = pack_bf16x2(o2, o3);
        o.z = pack_bf16x2(o4, o5);
        o.w = pack_bf16x2(o6, o7);
        *(uint4*)&x2p[(size_t)n * 64 + l16 * 4] = o;
    }
}

// ---------------------------------------------------------------------------
// Aggregation layer 2, GROUPED: 4 nodes/wave, 16 lanes/node, lane = 4 ch
// (uint2 gather).  Single head.  4-edge unroll.
// ---------------------------------------------------------------------------
__global__ __launch_bounds__(256) void aggregate2_kernel(const unsigned* __restrict__ h2p,
                                                         const float* __restrict__ es,
                                                         const float* __restrict__ ed,
                                                         const int* __restrict__ rowstart,
                                                         const int* __restrict__ csr_src,
                                                         const float* __restrict__ b,
                                                         float* __restrict__ out, int N) {
    const int lane = threadIdx.x & 63;
    const int w = (blockIdx.x * 256 + threadIdx.x) >> 6;
    const int l16 = lane & 15;
    const int n = w * 4 + (lane >> 4);
    const bool valid = n < N;
    const int nc = valid ? n : N - 1;
    const int beg = rowstart[nc];
    const int deg = valid ? rowstart[nc + 1] - beg : 0;
    const float edv = ed[nc];

    int dmax = deg;
    dmax = max(dmax, __shfl_xor(dmax, 16));
    dmax = max(dmax, __shfl_xor(dmax, 32));

    float acc0 = 0.f, acc1 = 0.f, acc2 = 0.f, acc3 = 0.f;
    float den = 0.f;
    for (int j = 0; j < dmax; j += 4) {
        const bool va = j < deg, vb = j + 1 < deg, vc = j + 2 < deg, vd = j + 3 < deg;
        const int pa_ = va ? beg + j : 0;
        const int pb_ = vb ? beg + j + 1 : 0;
        const int pc_ = vc ? beg + j + 2 : 0;
        const int pd_ = vd ? beg + j + 3 : 0;
        const int sa = csr_src[pa_];
        const int sb = csr_src[pb_];
        const int sc = csr_src[pc_];
        const int sd = csr_src[pd_];
        const uint2 ua = *(const uint2*)&h2p[(size_t)sa * 32 + l16 * 2];
        const uint2 ub = *(const uint2*)&h2p[(size_t)sb * 32 + l16 * 2];
        const uint2 uc = *(const uint2*)&h2p[(size_t)sc * 32 + l16 * 2];
        const uint2 ud = *(const uint2*)&h2p[(size_t)sd * 32 + l16 * 2];
        const float xa = es[sa] + edv;
        const float xb = es[sb] + edv;
        const float xc = es[sc] + edv;
        const float xd = es[sd] + edv;
        float qa = __expf(fmaxf(xa, 0.2f * xa));
        float qb = __expf(fmaxf(xb, 0.2f * xb));
        float qc = __expf(fmaxf(xc, 0.2f * xc));
        float qd = __expf(fmaxf(xd, 0.2f * xd));
        qa = va ? qa : 0.f;
        qb = vb ? qb : 0.f;
        qc = vc ? qc : 0.f;
        qd = vd ? qd : 0.f;
        den += (qa + qb) + (qc + qd);
        acc0 = fmaf(qa, bf_lo(ua.x), fmaf(qb, bf_lo(ub.x), fmaf(qc, bf_lo(uc.x), fmaf(qd, bf_lo(ud.x), acc0))));
        acc1 = fmaf(qa, bf_hi(ua.x), fmaf(qb, bf_hi(ub.x), fmaf(qc, bf_hi(uc.x), fmaf(qd, bf_hi(ud.x), acc1))));
        acc2 = fmaf(qa, bf_lo(ua.y), fmaf(qb, bf_lo(ub.y), fmaf(qc, bf_lo(uc.y), fmaf(qd, bf_lo(ud.y), acc2))));
        acc3 = fmaf(qa, bf_hi(ua.y), fmaf(qb, bf_hi(ub.y), fmaf(qc, bf_hi(uc.y), fmaf(qd, bf_hi(ud.y), acc3))));
    }
    if (valid) {
        const float inv = __builtin_amdgcn_rcpf(den);
        const float4 bv = *(const float4*)&b[l16 * 4];
        float4 o;
        o.x = fmaf(acc0, inv, bv.x);
        o.y = fmaf(acc1, inv, bv.y);
        o.z = fmaf(acc2, inv, bv.z);
        o.w = fmaf(acc3, inv, bv.w);
        *(float4*)&out[(size_t)n * 64 + l16 * 4] = o;
    }
}

// ---------------------------------------------------------------------------
extern "C" void kernel_launch(void* const* d_in, const int* in_sizes, int n_in,
                              void* d_out, int out_size, void* d_ws, size_t ws_size,
                              hipStream_t stream) {
    const float* x     = (const float*)d_in[0];
    const int*   ei    = (const int*)d_in[1];
    const float* W1    = (const float*)d_in[2];
    const float* asrc1 = (const float*)d_in[3];
    const float* adst1 = (const float*)d_in[4];
    const float* b1    = (const float*)d_in[5];
    const float* W2    = (const float*)d_in[6];
    const float* asrc2 = (const float*)d_in[7];
    const float* adst2 = (const float*)d_in[8];
    const float* b2    = (const float*)d_in[9];
    float* out = (float*)d_out;

    const int N = in_sizes[0] / 128;
    const int E = in_sizes[1] / 2;
    const int Etot = E + N;

    // workspace layout (~83 MB)
    char* p = (char*)d_ws;
    auto alloc = [&](size_t bytes) {
        char* q = p;
        p += (bytes + 255) & ~size_t(255);
        return q;
    };
    unsigned short* h1 = (unsigned short*)alloc((size_t)N * 128 * 2);  // bf16 h1
    unsigned* x2p      = (unsigned*)alloc((size_t)N * 64 * 4);         // bf16x2 x2
    unsigned short* h2 = (unsigned short*)alloc((size_t)N * 64 * 2);   // bf16 h2
    float* es1      = (float*)alloc((size_t)N * 4 * 4);
    float* ed1      = (float*)alloc((size_t)N * 4 * 4);
    float* es2      = (float*)alloc((size_t)N * 4);
    float* ed2      = (float*)alloc((size_t)N * 4);
    int*   deg      = (int*)alloc((size_t)N * 4);
    int*   excl     = (int*)alloc((size_t)N * 4);
    int*   bsum     = (int*)alloc(1024);
    int*   rowstart = (int*)alloc((size_t)(N + 1) * 4);
    int*   rank     = (int*)alloc((size_t)E * 4);
    int*   csr_src  = (int*)alloc((size_t)Etot * 4);
    unsigned* Wb1   = (unsigned*)alloc(2048 * 16);
    unsigned* Wb2   = (unsigned*)alloc(1024 * 16);

    const int nblk16 = (N + 63) / 64;       // MFMA gemms: 4 waves x 16 rows
    const int nwb4 = (N + 15) / 16;         // 4-nodes-per-wave agg kernels
    const int nchunks = (N + 2047) / 2048;  // <= 64 required (N <= 131072)

    // weight prep + deg zero-init (fused)
    prep_kernel<<<64, 256, 0, stream>>>(W1, W2, Wb1, Wb2, deg, N);

    // layer 1 projection (MFMA) + fused scores
    gemm1_kernel<<<nblk16, 256, 0, stream>>>(x, Wb1, asrc1, adst1, h1, es1, ed1, N);

    // CSR by destination (shared by both layers)
    rank_count_kernel<<<512, 256, 0, stream>>>(ei, E, deg, rank);
    scan_p1_kernel<<<nchunks, 256, 0, stream>>>(deg, excl, bsum, N);
    scan_p2_kernel<<<1, 64, 0, stream>>>(bsum, nchunks);
    scan_p3_kernel<<<(N + 255) / 256, 256, 0, stream>>>(excl, bsum, rowstart, N, Etot);
    csr_fill_kernel<<<(Etot + 255) / 256, 256, 0, stream>>>(ei, E, N, rowstart, rank, csr_src);

    // layer 1 aggregation (grouped, 4-edge ILP)
    aggregate1_kernel<<<nwb4, 256, 0, stream>>>((const unsigned*)h1, es1, ed1,
                                                rowstart, csr_src, b1, x2p, N);

    // layer 2
    gemm2_kernel<<<nblk16, 256, 0, stream>>>(x2p, Wb2, asrc2, adst2, h2, es2, ed2, N);
    aggregate2_kernel<<<nwb4, 256, 0, stream>>>((const unsigned*)h2, es2, ed2,
                                                rowstart, csr_src, b2, out, N);
}